// Round 11
// baseline (445.386 us; speedup 1.0000x reference)
//
#include <hip/hip_runtime.h>
#include <cstdint>
#include <cstddef>

typedef unsigned short ushort_t;
typedef short    bf16x8 __attribute__((ext_vector_type(8)));   // MFMA A/B frag (4 VGPR)
typedef float    f32x4  __attribute__((ext_vector_type(4)));   // MFMA C/D frag
typedef uint4    __attribute__((may_alias)) uint4_a;
typedef ushort4  __attribute__((may_alias)) ushort4_a;
typedef float4   __attribute__((may_alias)) float4_a;
typedef float2   __attribute__((may_alias)) float2_a;
typedef unsigned __attribute__((may_alias)) uint_a;

constexpr int SEQ = 4096, HID = 2048, NHEADS = 16, NKVH = 4, HDIM = 128;
constexpr int QD  = NHEADS * HDIM;   // 2048
constexpr int KVD = NKVH * HDIM;     // 512
constexpr int KVL = 2 * KVD;         // 1024: interleaved k|v row stride
constexpr int NPART = 56;            // partial chunks per head (t=16..23:3, t=24..31:4)

static __device__ __forceinline__ float bf2f(ushort_t u) {
    return __uint_as_float(((unsigned)u) << 16);
}
static __device__ __forceinline__ ushort_t f2bf(float f) {
    unsigned x = __float_as_uint(f);
    unsigned r = x + 0x7FFFu + ((x >> 16) & 1u);   // RNE
    return (ushort_t)(r >> 16);
}
static __device__ __forceinline__ unsigned pack2(float lo, float hi) {
    return (unsigned)f2bf(lo) | ((unsigned)f2bf(hi) << 16);
}
// HW packed f32->bf16 (RNE), 1 instr instead of ~7 (T12 primitive; no builtin on gfx950)
static __device__ __forceinline__ unsigned cvt_pk(float lo, float hi) {
    unsigned r;
    asm("v_cvt_pk_bf16_f32 %0, %1, %2" : "=v"(r) : "v"(lo), "v"(hi));
    return r;
}

// async global->LDS, 16B per lane; LDS dest = wave-uniform base + lane*16
static __device__ __forceinline__ void gld16(const ushort_t* g, ushort_t* l) {
    __builtin_amdgcn_global_load_lds(
        (const __attribute__((address_space(1))) unsigned*)g,
        (__attribute__((address_space(3))) unsigned*)l, 16, 0, 0);
}

// ---------------------------------------------------------------------------
// X fp32 -> bf16 elementwise
// ---------------------------------------------------------------------------
__global__ __launch_bounds__(256) void cast_f32_bf16(
    const float* __restrict__ in, ushort_t* __restrict__ out, int n)
{
    int i = (blockIdx.x * 256 + threadIdx.x) * 8;
    if (i >= n) return;
    float4 a = *(const float4_a*)(in + i);
    float4 b = *(const float4_a*)(in + i + 4);
    uint4 o;
    o.x = pack2(a.x, a.y); o.y = pack2(a.z, a.w);
    o.z = pack2(b.x, b.y); o.w = pack2(b.z, b.w);
    *(uint4_a*)(out + i) = o;
}

// ---------------------------------------------------------------------------
// W[K,N] fp32 -> WT[N,K] bf16 (32x32 LDS-tiled transpose+cast)
// ---------------------------------------------------------------------------
__global__ __launch_bounds__(256) void transpose_cast(
    const float* __restrict__ W, ushort_t* __restrict__ WT, int K, int N)
{
    __shared__ float tl[32][36];
    const int k0 = blockIdx.x * 32, n0 = blockIdx.y * 32;
    const int t  = threadIdx.x;
    {
        int i = t >> 3, jb = (t & 7) * 4;
        *(float4_a*)&tl[i][jb] = *(const float4_a*)(W + (size_t)(k0 + i) * N + n0 + jb);
    }
    __syncthreads();
    {
        int n = t >> 3, kb = (t & 7) * 4;
        ushort4 o;
        o.x = f2bf(tl[kb + 0][n]); o.y = f2bf(tl[kb + 1][n]);
        o.z = f2bf(tl[kb + 2][n]); o.w = f2bf(tl[kb + 3][n]);
        *(ushort4_a*)(WT + (size_t)(n0 + n) * K + k0 + kb) = o;
    }
}

// ---------------------------------------------------------------------------
// Fused wq|wk|wv transpose+cast -> wqkvT rows [0,2048)|[2048,2560)|[2560,3072)
// ---------------------------------------------------------------------------
__global__ __launch_bounds__(256) void transpose_cast_qkv(
    const float* __restrict__ wq, const float* __restrict__ wk,
    const float* __restrict__ wv, ushort_t* __restrict__ WT)
{
    __shared__ float tl[32][36];
    const int k0 = blockIdx.x * 32, nb = blockIdx.y * 32;
    const int t  = threadIdx.x;
    const float* W; int n0, N;
    if (nb < 2048)      { W = wq; n0 = nb;        N = QD;  }
    else if (nb < 2560) { W = wk; n0 = nb - 2048; N = KVD; }
    else                { W = wv; n0 = nb - 2560; N = KVD; }
    {
        int i = t >> 3, jb = (t & 7) * 4;
        *(float4_a*)&tl[i][jb] = *(const float4_a*)(W + (size_t)(k0 + i) * N + n0 + jb);
    }
    __syncthreads();
    {
        int n = t >> 3, kb = (t & 7) * 4;
        ushort4 o;
        o.x = f2bf(tl[kb + 0][n]); o.y = f2bf(tl[kb + 1][n]);
        o.z = f2bf(tl[kb + 2][n]); o.w = f2bf(tl[kb + 3][n]);
        *(ushort4_a*)(WT + (size_t)(nb + n) * HID + k0 + kb) = o;
    }
}

// ---------------------------------------------------------------------------
// m97-style MFMA GEMM: C = A[M,K] * Bt[N,K]^T, bf16 in, fp32 acc. 128x128
// tile, 4 waves. Used for the O-projection (N=2048 -> 256^2 would idle half
// the chip). Epilogue routes cols < split -> C1, else C2; out_f32 -> C1 fp32.
// ---------------------------------------------------------------------------
__global__ __launch_bounds__(256) void gemm_mfma(
    const ushort_t* __restrict__ A, int lda,
    const ushort_t* __restrict__ Bt, int ldb,
    void* __restrict__ C1, int ld1, void* __restrict__ C2, int ld2,
    int split, int N, int K, int out_f32)
{
    __shared__ ushort_t as[128 * 32];   // 8 KB, unpadded (dma-contiguous)
    __shared__ ushort_t bs[128 * 32];

    const int t    = threadIdx.x;
    const int mb   = blockIdx.y * 128, nb = blockIdx.x * 128;
    const int w    = t >> 6, lane = t & 63, quad = lane >> 4, l15 = lane & 15;
    const int wm   = (w >> 1) * 64, wn = (w & 1) * 64;

    const int dr_row = lane >> 2, dr_c = lane & 3;
    const int rA0 = w * 16 + dr_row, rA1 = 64 + w * 16 + dr_row;
    const ushort_t* a0p = A  + (size_t)(mb + rA0) * lda + (dr_c ^ (rA0 & 3)) * 8;
    const ushort_t* a1p = A  + (size_t)(mb + rA1) * lda + (dr_c ^ (rA1 & 3)) * 8;
    const ushort_t* b0p = Bt + (size_t)(nb + rA0) * ldb + (dr_c ^ (rA0 & 3)) * 8;
    const ushort_t* b1p = Bt + (size_t)(nb + rA1) * ldb + (dr_c ^ (rA1 & 3)) * 8;
    ushort_t* asb0 = &as[(w) * 512];        ushort_t* asb1 = &as[(4 + w) * 512];
    ushort_t* bsb0 = &bs[(w) * 512];        ushort_t* bsb1 = &bs[(4 + w) * 512];

    f32x4 acc[4][4];
#pragma unroll
    for (int i = 0; i < 4; i++)
#pragma unroll
        for (int j = 0; j < 4; j++) acc[i][j] = (f32x4)0.f;

    const int chunk = quad ^ (l15 & 3);   // swizzled frag chunk

    for (int kb = 0; kb < K; kb += 32) {
        __syncthreads();                   // prev iter's frag reads done
        gld16(a0p + kb, asb0);
        gld16(a1p + kb, asb1);
        gld16(b0p + kb, bsb0);
        gld16(b1p + kb, bsb1);
        __syncthreads();                   // compiler drains vmcnt before barrier

        bf16x8 af[4], bf[4];
#pragma unroll
        for (int mt = 0; mt < 4; mt++)
            af[mt] = *(const bf16x8*)&as[(wm + mt * 16 + l15) * 32 + chunk * 8];
#pragma unroll
        for (int nt = 0; nt < 4; nt++)
            bf[nt] = *(const bf16x8*)&bs[(wn + nt * 16 + l15) * 32 + chunk * 8];
#pragma unroll
        for (int mt = 0; mt < 4; mt++)
#pragma unroll
            for (int nt = 0; nt < 4; nt++)
                acc[mt][nt] = __builtin_amdgcn_mfma_f32_16x16x32_bf16(
                    af[mt], bf[nt], acc[mt][nt], 0, 0, 0);
    }

#pragma unroll
    for (int mt = 0; mt < 4; mt++)
#pragma unroll
        for (int nt = 0; nt < 4; nt++) {
            int colg = nb + wn + nt * 16 + l15;
#pragma unroll
            for (int r = 0; r < 4; r++) {
                int row = mb + wm + mt * 16 + quad * 4 + r;
                float v = acc[mt][nt][r];
                if (out_f32)            ((float*)C1)[(size_t)row * ld1 + colg] = v;
                else if (colg < split)  ((ushort_t*)C1)[(size_t)row * ld1 + colg] = f2bf(v);
                else                    ((ushort_t*)C2)[(size_t)row * ld2 + colg - split] = f2bf(v);
            }
        }
}

// ---------------------------------------------------------------------------
// 256^2 8-phase GEMM (R18): C = A[M,K] * Bt[N,K]^T, bf16, fp32 acc. Plain-HIP
// port of the 8-phase template (T2+T3+T4+T5): 512 thr = 8 waves (2M x 4N),
// per-wave output 128x64 (acc[8][4]), BK=64, LDS 128KB = 2 dbuf x 2 half x
// [128][64] per matrix, staged gld16-direct with chunk^=(row&7) XOR swizzle
// on BOTH sides (rule #21; same algebra as flash R16's proven K staging).
// Per K-tile: 4 phases, each = {stage half-tiles | 12-or-4 ds_read_b128 |
// raw s_barrier | lgkmcnt(0)+sched_barrier | setprio(1) 16 MFMA setprio(0) |
// raw s_barrier}. Staging for tile kt+1 all issued in phases 0-1 (2-3 phases
// of load slack); ONE vmcnt drain per K-tile at phase 3 (loads cross the
// phase barriers -- raw s_barrier has no auto-drain). Quadrants ordered so
// A-frags are read once per half and reused (phases 0/1 share af, 2/3 share).
// Grid must exactly tile M,N by 256. Epilogue: split/C1/C2 as gemm_mfma.
// ---------------------------------------------------------------------------
__global__ __launch_bounds__(512, 2) void gemm256(
    const ushort_t* __restrict__ A, int lda,
    const ushort_t* __restrict__ Bt, int ldb,
    void* __restrict__ C1, int ld1, void* __restrict__ C2, int ld2,
    int split, int K, int out_f32)
{
    __shared__ ushort_t as[2][2][8192];   // [dbuf][half][row*64 + chunk*8] 64KB
    __shared__ ushort_t bs[2][2][8192];   // 64KB

    const int t = threadIdx.x;
    const int w = t >> 6, lane = t & 63, quad = lane >> 4, l15 = lane & 15;
    const int wr = w >> 2, wc = w & 3;               // wave tile: rows wr*128, cols wc*64
    const int mb = blockIdx.y * 256, nb = blockIdx.x * 256;

    // staging map: thread t covers (row t>>3, phys chunk t&7) and (+64 rows)
    // of each 128-row half; logical source chunk = phys ^ (row&7) (row&7 ==
    // (t>>3)&7 for both rows). LDS dest is linear: slot t -> base + t*16B.
    const int arow = t >> 3;
    const int achk = ((t & 7) ^ (arow & 7)) * 8;
    const ushort_t* a0 = A  + (size_t)(mb + arow) * lda + achk;
    const ushort_t* a1 = A  + (size_t)(mb + 128 + arow) * lda + achk;
    const ushort_t* b0 = Bt + (size_t)(nb + arow) * ldb + achk;
    const ushort_t* b1 = Bt + (size_t)(nb + 128 + arow) * ldb + achk;

    auto stageA = [&](int kt, int h, int b) {
        const ushort_t* s = (h ? a1 : a0) + kt * 64;
        gld16(s, &as[b][h][w * 512]);
        gld16(s + (size_t)64 * lda, &as[b][h][4096 + w * 512]);
    };
    auto stageB = [&](int kt, int h, int b) {
        const ushort_t* s = (h ? b1 : b0) + kt * 64;
        gld16(s, &bs[b][h][w * 512]);
        gld16(s + (size_t)64 * ldb, &bs[b][h][4096 + w * 512]);
    };

    // frag read offsets (shorts): row_local = rep*16 + l15, phys chunk =
    // (ks*4+quad) ^ (l15&7)  [row_local&7 == l15&7]
    int aoff[2], boff[2];
#pragma unroll
    for (int ks = 0; ks < 2; ks++) {
        int pc = ((ks * 4 + quad) ^ (l15 & 7)) * 8;
        aoff[ks] = l15 * 64 + pc;
        boff[ks] = (wc & 1) * 4096 + l15 * 64 + pc;
    }

    f32x4 acc[8][4];
#pragma unroll
    for (int i = 0; i < 8; i++)
#pragma unroll
        for (int j = 0; j < 4; j++) acc[i][j] = (f32x4)0.f;

    const int nkt = K >> 6;

    // prologue: stage tile 0 fully into dbuf 0
    stageA(0, 0, 0); stageB(0, 0, 0);
    stageA(0, 1, 0); stageB(0, 1, 0);
    asm volatile("s_waitcnt vmcnt(0)" ::: "memory");
    __builtin_amdgcn_s_barrier();

    for (int kt = 0; kt < nkt; ++kt) {
        const int par = kt & 1;
        const bool more = (kt + 1 < nkt);
        const ushort_t* ab = &as[par][wr][0];
        const ushort_t* bb = &bs[par][wc >> 1][0];

        bf16x8 af[4][2], bf[2][2];

        // ---- phase 0: quadrant (m0-3 x n0-1); stage A/B h0 of kt+1 ----
        if (more) { stageA(kt + 1, 0, par ^ 1); stageB(kt + 1, 0, par ^ 1); }
#pragma unroll
        for (int mr = 0; mr < 4; mr++)
#pragma unroll
            for (int ks = 0; ks < 2; ks++)
                af[mr][ks] = *(const bf16x8*)&ab[mr * 1024 + aoff[ks]];
#pragma unroll
        for (int nr = 0; nr < 2; nr++)
#pragma unroll
            for (int ks = 0; ks < 2; ks++)
                bf[nr][ks] = *(const bf16x8*)&bb[nr * 1024 + boff[ks]];
        __builtin_amdgcn_s_barrier();
        asm volatile("s_waitcnt lgkmcnt(0)" ::: "memory");
        __builtin_amdgcn_sched_barrier(0);
        __builtin_amdgcn_s_setprio(1);
#pragma unroll
        for (int ks = 0; ks < 2; ks++)
#pragma unroll
            for (int mr = 0; mr < 4; mr++)
#pragma unroll
                for (int nr = 0; nr < 2; nr++)
                    acc[mr][nr] = __builtin_amdgcn_mfma_f32_16x16x32_bf16(
                        af[mr][ks], bf[nr][ks], acc[mr][nr], 0, 0, 0);
        __builtin_amdgcn_s_setprio(0);
        __builtin_amdgcn_s_barrier();

        // ---- phase 1: (m0-3 x n2-3), af reused; stage A/B h1 of kt+1 ----
        if (more) { stageA(kt + 1, 1, par ^ 1); stageB(kt + 1, 1, par ^ 1); }
#pragma unroll
        for (int nr = 0; nr < 2; nr++)
#pragma unroll
            for (int ks = 0; ks < 2; ks++)
                bf[nr][ks] = *(const bf16x8*)&bb[(nr + 2) * 1024 + boff[ks]];
        __builtin_amdgcn_s_barrier();
        asm volatile("s_waitcnt lgkmcnt(0)" ::: "memory");
        __builtin_amdgcn_sched_barrier(0);
        __builtin_amdgcn_s_setprio(1);
#pragma unroll
        for (int ks = 0; ks < 2; ks++)
#pragma unroll
            for (int mr = 0; mr < 4; mr++)
#pragma unroll
                for (int nr = 0; nr < 2; nr++)
                    acc[mr][nr + 2] = __builtin_amdgcn_mfma_f32_16x16x32_bf16(
                        af[mr][ks], bf[nr][ks], acc[mr][nr + 2], 0, 0, 0);
        __builtin_amdgcn_s_setprio(0);
        __builtin_amdgcn_s_barrier();

        // ---- phase 2: (m4-7 x n0-1) ----
#pragma unroll
        for (int mr = 0; mr < 4; mr++)
#pragma unroll
            for (int ks = 0; ks < 2; ks++)
                af[mr][ks] = *(const bf16x8*)&ab[(mr + 4) * 1024 + aoff[ks]];
#pragma unroll
        for (int nr = 0; nr < 2; nr++)
#pragma unroll
            for (int ks = 0; ks < 2; ks++)
                bf[nr][ks] = *(const bf16x8*)&bb[nr * 1024 + boff[ks]];
        __builtin_amdgcn_s_barrier();
        asm volatile("s_waitcnt lgkmcnt(0)" ::: "memory");
        __builtin_amdgcn_sched_barrier(0);
        __builtin_amdgcn_s_setprio(1);
#pragma unroll
        for (int ks = 0; ks < 2; ks++)
#pragma unroll
            for (int mr = 0; mr < 4; mr++)
#pragma unroll
                for (int nr = 0; nr < 2; nr++)
                    acc[mr + 4][nr] = __builtin_amdgcn_mfma_f32_16x16x32_bf16(
                        af[mr][ks], bf[nr][ks], acc[mr + 4][nr], 0, 0, 0);
        __builtin_amdgcn_s_setprio(0);
        __builtin_amdgcn_s_barrier();

        // ---- phase 3: (m4-7 x n2-3); drain kt+1's loads, boundary barrier ----
#pragma unroll
        for (int nr = 0; nr < 2; nr++)
#pragma unroll
            for (int ks = 0; ks < 2; ks++)
                bf[nr][ks] = *(const bf16x8*)&bb[(nr + 2) * 1024 + boff[ks]];
        __builtin_amdgcn_s_barrier();
        asm volatile("s_waitcnt lgkmcnt(0)" ::: "memory");
        __builtin_amdgcn_sched_barrier(0);
        __builtin_amdgcn_s_setprio(1);
#pragma unroll
        for (int ks = 0; ks < 2; ks++)
#pragma unroll
            for (int mr = 0; mr < 4; mr++)
#pragma unroll
                for (int nr = 0; nr < 2; nr++)
                    acc[mr + 4][nr + 2] = __builtin_amdgcn_mfma_f32_16x16x32_bf16(
                        af[mr][ks], bf[nr][ks], acc[mr + 4][nr + 2], 0, 0, 0);
        __builtin_amdgcn_s_setprio(0);
        if (more) asm volatile("s_waitcnt vmcnt(0)" ::: "memory");
        __builtin_amdgcn_s_barrier();
    }

    // ---- epilogue ----
#pragma unroll
    for (int mrep = 0; mrep < 8; mrep++)
#pragma unroll
        for (int nrep = 0; nrep < 4; nrep++) {
            int colg = nb + wc * 64 + nrep * 16 + l15;
#pragma unroll
            for (int r = 0; r < 4; r++) {
                int row = mb + wr * 128 + mrep * 16 + quad * 4 + r;
                float v = acc[mrep][nrep][r];
                if (out_f32)            ((float*)C1)[(size_t)row * ld1 + colg] = v;
                else if (colg < split)  ((ushort_t*)C1)[(size_t)row * ld1 + colg] = f2bf(v);
                else                    ((ushort_t*)C2)[(size_t)row * ld2 + colg - split] = f2bf(v);
            }
        }
}

// ---------------------------------------------------------------------------
// RoPE in-place on Q [SEQ,QD] and KV [SEQ,KVL] bf16 buffers in ONE launch
// ---------------------------------------------------------------------------
__global__ __launch_bounds__(256) void rope_both(
    ushort_t* __restrict__ qb, ushort_t* __restrict__ kvb,
    const int* __restrict__ pos_ids)
{
    int idx  = blockIdx.x * 256 + threadIdx.x;
    int i    = idx & 63;
    int rem  = idx >> 6;
    int hs   = rem % (NHEADS + NKVH);
    int s    = rem / (NHEADS + NKVH);
    if (s >= SEQ) return;

    float pos = (float)pos_ids[s];
    float ang = pos * __expf(-(float)i * 0.14391156831212787f);
    float c, sn;
    sincosf(ang, &sn, &c);

    ushort_t* p = (hs < NHEADS)
        ? qb  + (size_t)s * QD  + hs * HDIM
        : kvb + (size_t)s * KVL + (hs - NHEADS) * HDIM;
    float x0 = bf2f(p[i]);
    float x1 = bf2f(p[i + 64]);
    p[i]      = f2bf(x0 * c - x1 * sn);
    p[i + 64] = f2bf(x1 * c + x0 * sn);
}

// ---------------------------------------------------------------------------
// Flash attention v12 (R16/R17, best: 171us): split-K + single-barrier LDS
// double-buffer + gld16-direct K staging. Unchanged this round.
// ---------------------------------------------------------------------------
__global__ __launch_bounds__(512, 4) void flash_mfma(
    const ushort_t* Q, const ushort_t* __restrict__ KV,
    const int* __restrict__ amask, ushort_t* O,
    ushort_t* __restrict__ Opart, float2* __restrict__ ML)
{
    __shared__ ushort_t ks[2][64 * 128];   // 32 KB: K dbuf, swizzled chunks
    __shared__ ushort_t vt[2][128 * 72];   // 36 KB: V^T dbuf, padded rows
    __shared__ float    bias[2][64];       // 0.5 KB

    const int t = threadIdx.x, w = t >> 6, lane = t & 63;
    const int quad = lane >> 4, l15 = lane & 15;
    const int h = blockIdx.x, kvh = h >> 2;
    const int s = blockIdx.y;                        // slot 0..71
    const int kcol = kvh * HDIM, vcol = KVD + kvh * HDIM;
    const float scale2 = 0.08838834764831845f * 1.44269504088896340f; // /sqrt(128)*log2e

    // slot -> (tile, chunk range, partial id)
    int tile, ktb, kte, pid;
    bool multi;
    if (s < 8)       { tile = 15 - s;        ktb = 0; kte = 2 * tile + 2; multi = false; pid = 0; }
    else if (s < 64) {
        int cs = s - 8;                               // 0..55
        int c;
        if (cs < 24) { tile = 16 + cs / 3; c = cs - (tile - 16) * 3; }
        else         { int d = cs - 24; tile = 24 + (d >> 2); c = d & 3; }
        int nkt = 2 * tile + 2;
        ktb = c * 16; kte = (ktb + 16 < nkt) ? ktb + 16 : nkt;
        multi = true; pid = h * NPART + cs;
    }
    else             { tile = 7 - (s - 64);  ktb = 0; kte = 2 * tile + 2; multi = false; pid = 0; }

    const int q0  = tile * 128;
    const int q0w = q0 + w * 16;

    // K gld16 map: 512 thr, 2 rounds; round r: row R = r*32 + (w*4+quad),
    // phys chunk l15, logical chunk = l15 ^ (R&7) (R&7 same both rounds).
    const int kRow = w * 4 + quad;                   // 0..31
    const int klc  = l15 ^ (kRow & 7);               // logical chunk
    // V staging map (reg transpose): keys 2vkp,2vkp+1, dims vdg*8..+8
    const int vkp  = t & 31,  vdg = t >> 5;

    // bpermute indices for P transpose: quad' = 2*(quad&1) + (t4>>1)
    int bpi[4];
#pragma unroll
    for (int t4 = 0; t4 < 4; t4++)
        bpi[t4] = ((2 * (quad & 1) + (t4 >> 1)) * 16 + l15) * 4;
    const bool hi_half = (quad >> 1) != 0;           // selects mt' = 2kc+1

    // physical chunk byte-offsets for QK^T frag reads: row&7 == l15&7
    int pco[4];
#pragma unroll
    for (int c = 0; c < 4; c++)
        pco[c] = ((4 * c + quad) ^ (l15 & 7)) * 8;

    // Q B-frags: qf[c] = Q[q0w + l15][c*32 + quad*8 ..+8]
    bf16x8 qf[4];
    {
        const ushort_t* qp = Q + (size_t)(q0w + l15) * QD + h * HDIM;
#pragma unroll
        for (int c = 0; c < 4; c++)
            qf[c] = *(const bf16x8*)(qp + c * 32 + quad * 8);
    }

    f32x4 accO[8];
#pragma unroll
    for (int j = 0; j < 8; j++) accO[j] = (f32x4)0.f;
    float m_s = -1e30f, l_s = 0.f;

    uint4 va, vb;
    float bst = 0.f;
    auto stage_k = [&](int kt, int b) {              // async K -> LDS (direct)
        const ushort_t* g0 = KV + (size_t)(kt * 64 + kRow) * KVL + kcol + klc * 8;
        gld16(g0, &ks[b][w * 512]);
        gld16(g0 + (size_t)32 * KVL, &ks[b][4096 + w * 512]);
    };
    auto vload = [&](int kt) {                       // V global -> regs
        const ushort_t* vp = KV + (size_t)(kt * 64 + 2 * vkp) * KVL + vcol + vdg * 8;
        va = *(const uint4_a*)vp;
        vb = *(const uint4_a*)(vp + KVL);
        bst = (t < 64) ? (amask[kt * 64 + t] ? 0.f : -1e30f) : 0.f;
    };
    auto vstore = [&](int b) {                       // regs -> vt[b] (transposed)
        unsigned aw[4] = {va.x, va.y, va.z, va.w};
        unsigned bw[4] = {vb.x, vb.y, vb.z, vb.w};
#pragma unroll
        for (int i = 0; i < 4; i++) {
            *(uint_a*)&vt[b][(vdg * 8 + 2 * i) * 72 + 2 * vkp] =
                (aw[i] & 0xFFFFu) | (bw[i] << 16);
            *(uint_a*)&vt[b][(vdg * 8 + 2 * i + 1) * 72 + 2 * vkp] =
                (aw[i] >> 16) | (bw[i] & 0xFFFF0000u);
        }
        if (t < 64) bias[b][t] = bst;
    };

    // prologue: stage tile ktb into buffer 0
    stage_k(ktb, 0);
    vload(ktb);
    vstore(0);
    __syncthreads();   // drains gld16 + ds_writes (compiler vmcnt/lgkmcnt)

    for (int kt = ktb; kt < kte; kt++) {
        const int cur = (kt - ktb) & 1;
        const int k0 = kt * 64;
        const bool more = (kt + 1 < kte);
        if (more) {                       // issue next-tile loads early (T14)
            stage_k(kt + 1, cur ^ 1);
            vload(kt + 1);
        }

        if (k0 <= q0w + 15) {             // tile not fully masked for this wave
            // ---- S^T = K Q^T ----
            f32x4 sx[4];
#pragma unroll
            for (int mt = 0; mt < 4; mt++) sx[mt] = (f32x4)0.f;
            __builtin_amdgcn_s_setprio(1);
#pragma unroll
            for (int c = 0; c < 4; c++)
#pragma unroll
                for (int mt = 0; mt < 4; mt++) {
                    bf16x8 kf = *(const bf16x8*)&ks[cur][(mt * 16 + l15) * 128 + pco[c]];
                    sx[mt] = __builtin_amdgcn_mfma_f32_16x16x32_bf16(kf, qf[c], sx[mt], 0, 0, 0);
                }
            __builtin_amdgcn_s_setprio(0);

            // ---- masked online softmax (exp2 domain); q-row = l15 ----
            const int qg = q0w + l15;
            const bool full = (k0 + 63 <= q0w);
            float p[4][4];
            float mx = -1e30f;
#pragma unroll
            for (int mt = 0; mt < 4; mt++) {
                float4 b4 = *(const float4_a*)&bias[cur][mt * 16 + quad * 4];
                float br[4] = {b4.x, b4.y, b4.z, b4.w};
#pragma unroll
                for (int r = 0; r < 4; r++) {
                    float v = fmaf(sx[mt][r], scale2, br[r]);
                    if (!full) {
                        int kg = k0 + mt * 16 + quad * 4 + r;
                        v = (kg > qg) ? -1e30f : v;
                    }
                    p[mt][r] = v;
                    mx = fmaxf(mx, v);
                }
            }
            mx = fmaxf(mx, __shfl_xor(mx, 16));
            mx = fmaxf(mx, __shfl_xor(mx, 32));
            // defer-max (T13): keep old max unless it grew by >8
            const bool renorm = !__all(mx <= m_s + 8.f);
            const float mnew = renorm ? fmaxf(m_s, mx) : m_s;
            float sum = 0.f;
            unsigned wlo[4], whi[4];
#pragma unroll
            for (int mt = 0; mt < 4; mt++) {
                float p0 = exp2f(p[mt][0] - mnew);
                float p1 = exp2f(p[mt][1] - mnew);
                float p2 = exp2f(p[mt][2] - mnew);
                float p3 = exp2f(p[mt][3] - mnew);
                sum += (p0 + p1) + (p2 + p3);
                wlo[mt] = cvt_pk(p0, p1);
                whi[mt] = cvt_pk(p2, p3);
            }
            sum += __shfl_xor(sum, 16);
            sum += __shfl_xor(sum, 32);

            if (renorm) {
                float alpha = exp2f(m_s - mnew);
                l_s *= alpha;
                float a0 = __shfl(alpha, quad * 4 + 0);
                float a1 = __shfl(alpha, quad * 4 + 1);
                float a2 = __shfl(alpha, quad * 4 + 2);
                float a3 = __shfl(alpha, quad * 4 + 3);
#pragma unroll
                for (int j = 0; j < 8; j++) {
                    f32x4 a = accO[j];
                    a[0] *= a0; a[1] *= a1; a[2] *= a2; a[3] *= a3;
                    accO[j] = a;
                }
            }
            m_s = mnew;
            l_s += sum;

            // ---- P transpose C->A layout via ds_bpermute; then O += P V ----
#pragma unroll
            for (int kc = 0; kc < 2; kc++) {
                union { unsigned u[4]; bf16x8 v; } pf;
#pragma unroll
                for (int t4 = 0; t4 < 4; t4++) {
                    unsigned slo = (t4 & 1) ? whi[2 * kc]     : wlo[2 * kc];
                    unsigned shi = (t4 & 1) ? whi[2 * kc + 1] : wlo[2 * kc + 1];
                    int ra = __builtin_amdgcn_ds_bpermute(bpi[t4], (int)slo);
                    int rb = __builtin_amdgcn_ds_bpermute(bpi[t4], (int)shi);
                    pf.u[t4] = (unsigned)(hi_half ? rb : ra);
                }
                __builtin_amdgcn_s_setprio(1);
#pragma unroll
                for (int n8 = 0; n8 < 8; n8++) {
                    bf16x8 vf = *(const bf16x8*)&vt[cur][(n8 * 16 + l15) * 72 + kc * 32 + quad * 8];
                    accO[n8] = __builtin_amdgcn_mfma_f32_16x16x32_bf16(pf.v, vf, accO[n8], 0, 0, 0);
                }
                __builtin_amdgcn_s_setprio(0);
            }
        }

        if (more) vstore(cur ^ 1);        // write-late: V regs -> other buffer
        __syncthreads();                  // single barrier: buf[cur] reads done,
                                          // gld16/ds_writes drained for next iter
    }

    if (!multi) {
        // ---- epilogue: normalize rows, store bf16 in-place over Q region ----
        float linv = 1.0f / l_s;
#pragma unroll
        for (int r = 0; r < 4; r++) {
            float lr = __shfl(linv, quad * 4 + r);
            int row = q0w + quad * 4 + r;
            ushort_t* op = O + (size_t)row * QD + h * HDIM;
#pragma unroll
            for (int n8 = 0; n8 < 8; n8++)
                op[n8 * 16 + l15] = f2bf(accO[n8][r] * lr);
        }
    } else {
        // ---- partial epilogue: unnormalized accO (bf16) + per-row (m,l) ----
        ushort_t* op = Opart + (size_t)pid * (128 * 128);
#pragma unroll
        for (int r = 0; r < 4; r++) {
            int row = w * 16 + quad * 4 + r;
#pragma unroll
            for (int n8 = 0; n8 < 8; n8++)
                op[row * 128 + n8 * 16 + l15] = f2bf(accO[n8][r]);
        }
        if (quad == 0)
            ML[pid * 128 + w * 16 + l15] = make_float2(m_s, l_s);
    }
}

// ---------------------------------------------------------------------------
// Merge split-K partials for tiles t=16..31 (coalesced): per-row weights
// wc[c][row] = 2^(m_c - M)/L precomputed in LDS; 8 lanes cover one row's
// 128B contiguous span (read AND write dense). 256 blocks (h, t), 256 thr.
// ---------------------------------------------------------------------------
__global__ __launch_bounds__(256) void combine_partials(
    const ushort_t* __restrict__ P, const float2* __restrict__ ML,
    ushort_t* __restrict__ O)
{
    __shared__ float wc[4][128];
    const int h = blockIdx.x >> 4, tt = blockIdx.x & 15, tile = 16 + tt;
    const int nc = (tile < 24) ? 3 : 4;
    const int pid0 = h * NPART + ((tile < 24) ? tt * 3 : 24 + (tile - 24) * 4);
    const int tid = threadIdx.x;

    if (tid < 128) {
        const int row = tid;
        float m_[4], l_[4];
        float M = -1e30f;
#pragma unroll
        for (int c = 0; c < 4; c++) {
            if (c < nc) {
                float2 v = *(const float2_a*)&ML[(pid0 + c) * 128 + row];
                m_[c] = v.x; l_[c] = v.y; M = fmaxf(M, v.x);
            } else { m_[c] = -1e30f; l_[c] = 0.f; }
        }
        float L = 0.f, wgt[4];
#pragma unroll
        for (int c = 0; c < 4; c++) { wgt[c] = exp2f(m_[c] - M); L += wgt[c] * l_[c]; }
        const float inv = 1.0f / L;
#pragma unroll
        for (int c = 0; c < 4; c++) wc[c][row] = (c < nc) ? wgt[c] * inv : 0.f;
    }
    __syncthreads();

#pragma unroll
    for (int p = 0; p < 4; p++) {
        const int idx = p * 256 + tid;
        const int row = idx >> 3, seg = idx & 7;     // 16 cols per seg
        const size_t pb = (size_t)row * 128 + seg * 16;
        float acc[16];
#pragma unroll
        for (int j = 0; j < 16; j++) acc[j] = 0.f;
#pragma unroll
        for (int c = 0; c < 4; c++) {
            if (c < nc) {
                const ushort_t* pp = P + (size_t)(pid0 + c) * (128 * 128) + pb;
                uint4 v0 = *(const uint4_a*)pp;
                uint4 v1 = *(const uint4_a*)(pp + 8);
                const float wv_ = wc[c][row];
                unsigned u[8] = {v0.x, v0.y, v0.z, v0.w, v1.x, v1.y, v1.z, v1.w};
#pragma unroll
                for (int j = 0; j < 8; j++) {
                    acc[2 * j]     += wv_ * bf2f((ushort_t)(u[j] & 0xFFFFu));
                    acc[2 * j + 1] += wv_ * bf2f((ushort_t)(u[j] >> 16));
                }
            }
        }
        ushort_t* op = O + (size_t)(tile * 128 + row) * QD + h * HDIM + seg * 16;
        uint4 o0, o1;
        o0.x = pack2(acc[0],  acc[1]);  o0.y = pack2(acc[2],  acc[3]);
        o0.z = pack2(acc[4],  acc[5]);  o0.w = pack2(acc[6],  acc[7]);
        o1.x = pack2(acc[8],  acc[9]);  o1.y = pack2(acc[10], acc[11]);
        o1.z = pack2(acc[12], acc[13]); o1.w = pack2(acc[14], acc[15]);
        *(uint4_a*)op       = o0;
        *(uint4_a*)(op + 8) = o1;
    }
}

// ---------------------------------------------------------------------------
// Memory plan: ws = qbuf/att 16MB | kvbuf (k|v interleaved) 8MB | (woT 8MB
// overwrites kvbuf after flash+combine). d_out scratch: wqkvT 12MB | xb 16MB
// until QKV GEMM; then flash partials: Opart 28MB | ML 0.9MB; O-GEMM output
// overwrites after combine.
// ---------------------------------------------------------------------------
extern "C" void kernel_launch(void* const* d_in, const int* in_sizes, int n_in,
                              void* d_out, int out_size, void* d_ws, size_t ws_size,
                              hipStream_t stream)
{
    const float* x     = (const float*)d_in[0];
    const int*   amask = (const int*)d_in[1];
    const int*   pos   = (const int*)d_in[2];
    const float* wq    = (const float*)d_in[3];
    const float* wk    = (const float*)d_in[4];
    const float* wv    = (const float*)d_in[5];
    const float* wo    = (const float*)d_in[6];
    float* out = (float*)d_out;

    ushort_t* wqkvT = (ushort_t*)d_out;                    // [3072][2048] bf16
    ushort_t* xb    = wqkvT + (size_t)3072 * HID;          // [4096][2048] bf16

    ushort_t* qbuf  = (ushort_t*)d_ws;                     // [4096][2048]
    ushort_t* kvbuf = qbuf + (size_t)SEQ * QD;             // [4096][1024] k|v
    ushort_t* woT   = kvbuf;                               // [2048][2048] after flash

    // split-K partials live in d_out during attention
    ushort_t* opart = (ushort_t*)d_out;                    // 896 x 128 x 128 bf16 = 28MB
    float2*   mlbuf = (float2*)((char*)d_out + (size_t)16 * NPART * 128 * 128 * 2);

    cast_f32_bf16<<<SEQ * HID / 8 / 256, 256, 0, stream>>>(x, xb, SEQ * HID);
    // fused wq|wk|wv transpose (one launch)
    transpose_cast_qkv<<<dim3(HID / 32, 3072 / 32), 256, 0, stream>>>(wq, wk, wv, wqkvT);

    // fused QKV projection (8-phase 256^2): cols [0,2048)->qbuf, [2048,3072)->kvbuf
    gemm256<<<dim3(3072 / 256, SEQ / 256), 512, 0, stream>>>(
        xb, HID, wqkvT, HID, qbuf, QD, kvbuf, KVL, QD, HID, 0);

    // fused RoPE on Q and KV in one launch
    rope_both<<<SEQ * (NHEADS + NKVH) * 64 / 256, 256, 0, stream>>>(qbuf, kvbuf, pos);

    // split-K flash: 16 heads x 72 slots = 1152 blocks, 2 resident/CU + backfill
    flash_mfma<<<dim3(NHEADS, 72), 512, 0, stream>>>(
        qbuf, kvbuf, amask, qbuf, opart, mlbuf);
    combine_partials<<<dim3(256), 256, 0, stream>>>(opart, mlbuf, qbuf);

    transpose_cast<<<dim3(QD / 32, HID / 32), 256, 0, stream>>>(wo, woT, QD, HID);
    gemm_mfma<<<dim3(HID / 128, SEQ / 128), 256, 0, stream>>>(
        qbuf, QD, woT, QD, out, HID, out, HID, HID, HID, QD, 1);
}

// Round 13
// 423.289 us; speedup vs baseline: 1.0522x; 1.0522x over previous
//
#include <hip/hip_runtime.h>
#include <cstdint>
#include <cstddef>

typedef unsigned short ushort_t;
typedef short    bf16x8 __attribute__((ext_vector_type(8)));   // MFMA A/B frag (4 VGPR)
typedef float    f32x4  __attribute__((ext_vector_type(4)));   // MFMA C/D frag
typedef uint4    __attribute__((may_alias)) uint4_a;
typedef ushort4  __attribute__((may_alias)) ushort4_a;
typedef float4   __attribute__((may_alias)) float4_a;
typedef float2   __attribute__((may_alias)) float2_a;
typedef unsigned __attribute__((may_alias)) uint_a;

constexpr int SEQ = 4096, HID = 2048, NHEADS = 16, NKVH = 4, HDIM = 128;
constexpr int QD  = NHEADS * HDIM;   // 2048
constexpr int KVD = NKVH * HDIM;     // 512
constexpr int KVL = 2 * KVD;         // 1024: interleaved k|v row stride
constexpr int NPART = 56;            // partial chunks per head (t=16..23:3, t=24..31:4)

static __device__ __forceinline__ float bf2f(ushort_t u) {
    return __uint_as_float(((unsigned)u) << 16);
}
static __device__ __forceinline__ ushort_t f2bf(float f) {
    unsigned x = __float_as_uint(f);
    unsigned r = x + 0x7FFFu + ((x >> 16) & 1u);   // RNE
    return (ushort_t)(r >> 16);
}
static __device__ __forceinline__ unsigned pack2(float lo, float hi) {
    return (unsigned)f2bf(lo) | ((unsigned)f2bf(hi) << 16);
}
// HW packed f32->bf16 (RNE), 1 instr instead of ~7 (T12 primitive; no builtin on gfx950)
static __device__ __forceinline__ unsigned cvt_pk(float lo, float hi) {
    unsigned r;
    asm("v_cvt_pk_bf16_f32 %0, %1, %2" : "=v"(r) : "v"(lo), "v"(hi));
    return r;
}

// async global->LDS, 16B per lane; LDS dest = wave-uniform base + lane*16
static __device__ __forceinline__ void gld16(const ushort_t* g, ushort_t* l) {
    __builtin_amdgcn_global_load_lds(
        (const __attribute__((address_space(1))) unsigned*)g,
        (__attribute__((address_space(3))) unsigned*)l, 16, 0, 0);
}

// ---------------------------------------------------------------------------
// Fused prologue (R20): blocks [0,4096) cast X fp32->bf16 (8 elems/thread);
// blocks [4096,10240) transpose+cast wq|wk|wv -> wqkvT rows
// [0,2048)|[2048,2560)|[2560,3072). One launch instead of two.
// ---------------------------------------------------------------------------
__global__ __launch_bounds__(256) void prep(
    const float* __restrict__ x, ushort_t* __restrict__ xb,
    const float* __restrict__ wq, const float* __restrict__ wk,
    const float* __restrict__ wv, ushort_t* __restrict__ WT)
{
    __shared__ float tl[32][36];
    const int b = blockIdx.x, t = threadIdx.x;
    if (b < 4096) {
        int i = (b * 256 + t) * 8;
        float4 a = *(const float4_a*)(x + i);
        float4 c = *(const float4_a*)(x + i + 4);
        uint4 o;
        o.x = pack2(a.x, a.y); o.y = pack2(a.z, a.w);
        o.z = pack2(c.x, c.y); o.w = pack2(c.z, c.w);
        *(uint4_a*)(xb + i) = o;
        return;
    }
    const int tq = b - 4096;
    const int k0 = (tq & 63) * 32, nb = (tq >> 6) * 32;
    const float* W; int n0, N;
    if (nb < 2048)      { W = wq; n0 = nb;        N = QD;  }
    else if (nb < 2560) { W = wk; n0 = nb - 2048; N = KVD; }
    else                { W = wv; n0 = nb - 2560; N = KVD; }
    {
        int i = t >> 3, jb = (t & 7) * 4;
        *(float4_a*)&tl[i][jb] = *(const float4_a*)(W + (size_t)(k0 + i) * N + n0 + jb);
    }
    __syncthreads();
    {
        int n = t >> 3, kb = (t & 7) * 4;
        ushort4 o;
        o.x = f2bf(tl[kb + 0][n]); o.y = f2bf(tl[kb + 1][n]);
        o.z = f2bf(tl[kb + 2][n]); o.w = f2bf(tl[kb + 3][n]);
        *(ushort4_a*)(WT + (size_t)(nb + n) * HID + k0 + kb) = o;
    }
}

// ---------------------------------------------------------------------------
// W[K,N] fp32 -> WT[N,K] bf16 (32x32 LDS-tiled transpose+cast) -- for wo.
// ---------------------------------------------------------------------------
__global__ __launch_bounds__(256) void transpose_cast(
    const float* __restrict__ W, ushort_t* __restrict__ WT, int K, int N)
{
    __shared__ float tl[32][36];
    const int k0 = blockIdx.x * 32, n0 = blockIdx.y * 32;
    const int t  = threadIdx.x;
    {
        int i = t >> 3, jb = (t & 7) * 4;
        *(float4_a*)&tl[i][jb] = *(const float4_a*)(W + (size_t)(k0 + i) * N + n0 + jb);
    }
    __syncthreads();
    {
        int n = t >> 3, kb = (t & 7) * 4;
        ushort4 o;
        o.x = f2bf(tl[kb + 0][n]); o.y = f2bf(tl[kb + 1][n]);
        o.z = f2bf(tl[kb + 2][n]); o.w = f2bf(tl[kb + 3][n]);
        *(ushort4_a*)(WT + (size_t)(n0 + n) * K + k0 + kb) = o;
    }
}

// ---------------------------------------------------------------------------
// m97-style MFMA GEMM: C = A[M,K] * Bt[N,K]^T, bf16 in, fp32 acc. 128x128
// tile, 4 waves. R18 lesson: 256^2 tiles need grid >= 256 blocks (QKV=192,
// O=128 -> chip underfill loses more than the 8-phase schedule gains).
// Epilogue routes cols < split -> C1, else C2; out_f32 -> C1 fp32.
// ---------------------------------------------------------------------------
__global__ __launch_bounds__(256) void gemm_mfma(
    const ushort_t* __restrict__ A, int lda,
    const ushort_t* __restrict__ Bt, int ldb,
    void* __restrict__ C1, int ld1, void* __restrict__ C2, int ld2,
    int split, int N, int K, int out_f32)
{
    __shared__ ushort_t as[128 * 32];   // 8 KB, unpadded (dma-contiguous)
    __shared__ ushort_t bs[128 * 32];

    const int t    = threadIdx.x;
    const int mb   = blockIdx.y * 128, nb = blockIdx.x * 128;
    const int w    = t >> 6, lane = t & 63, quad = lane >> 4, l15 = lane & 15;
    const int wm   = (w >> 1) * 64, wn = (w & 1) * 64;

    const int dr_row = lane >> 2, dr_c = lane & 3;
    const int rA0 = w * 16 + dr_row, rA1 = 64 + w * 16 + dr_row;
    const ushort_t* a0p = A  + (size_t)(mb + rA0) * lda + (dr_c ^ (rA0 & 3)) * 8;
    const ushort_t* a1p = A  + (size_t)(mb + rA1) * lda + (dr_c ^ (rA1 & 3)) * 8;
    const ushort_t* b0p = Bt + (size_t)(nb + rA0) * ldb + (dr_c ^ (rA0 & 3)) * 8;
    const ushort_t* b1p = Bt + (size_t)(nb + rA1) * ldb + (dr_c ^ (rA1 & 3)) * 8;
    ushort_t* asb0 = &as[(w) * 512];        ushort_t* asb1 = &as[(4 + w) * 512];
    ushort_t* bsb0 = &bs[(w) * 512];        ushort_t* bsb1 = &bs[(4 + w) * 512];

    f32x4 acc[4][4];
#pragma unroll
    for (int i = 0; i < 4; i++)
#pragma unroll
        for (int j = 0; j < 4; j++) acc[i][j] = (f32x4)0.f;

    const int chunk = quad ^ (l15 & 3);   // swizzled frag chunk

    for (int kb = 0; kb < K; kb += 32) {
        __syncthreads();                   // prev iter's frag reads done
        gld16(a0p + kb, asb0);
        gld16(a1p + kb, asb1);
        gld16(b0p + kb, bsb0);
        gld16(b1p + kb, bsb1);
        __syncthreads();                   // compiler drains vmcnt before barrier

        bf16x8 af[4], bf[4];
#pragma unroll
        for (int mt = 0; mt < 4; mt++)
            af[mt] = *(const bf16x8*)&as[(wm + mt * 16 + l15) * 32 + chunk * 8];
#pragma unroll
        for (int nt = 0; nt < 4; nt++)
            bf[nt] = *(const bf16x8*)&bs[(wn + nt * 16 + l15) * 32 + chunk * 8];
#pragma unroll
        for (int mt = 0; mt < 4; mt++)
#pragma unroll
            for (int nt = 0; nt < 4; nt++)
                acc[mt][nt] = __builtin_amdgcn_mfma_f32_16x16x32_bf16(
                    af[mt], bf[nt], acc[mt][nt], 0, 0, 0);
    }

#pragma unroll
    for (int mt = 0; mt < 4; mt++)
#pragma unroll
        for (int nt = 0; nt < 4; nt++) {
            int colg = nb + wn + nt * 16 + l15;
#pragma unroll
            for (int r = 0; r < 4; r++) {
                int row = mb + wm + mt * 16 + quad * 4 + r;
                float v = acc[mt][nt][r];
                if (out_f32)            ((float*)C1)[(size_t)row * ld1 + colg] = v;
                else if (colg < split)  ((ushort_t*)C1)[(size_t)row * ld1 + colg] = f2bf(v);
                else                    ((ushort_t*)C2)[(size_t)row * ld2 + colg - split] = f2bf(v);
            }
        }
}

// ---------------------------------------------------------------------------
// RoPE in-place on Q [SEQ,QD] and KV [SEQ,KVL] bf16 buffers in ONE launch
// ---------------------------------------------------------------------------
__global__ __launch_bounds__(256) void rope_both(
    ushort_t* __restrict__ qb, ushort_t* __restrict__ kvb,
    const int* __restrict__ pos_ids)
{
    int idx  = blockIdx.x * 256 + threadIdx.x;
    int i    = idx & 63;
    int rem  = idx >> 6;
    int hs   = rem % (NHEADS + NKVH);
    int s    = rem / (NHEADS + NKVH);
    if (s >= SEQ) return;

    float pos = (float)pos_ids[s];
    float ang = pos * __expf(-(float)i * 0.14391156831212787f);
    float c, sn;
    sincosf(ang, &sn, &c);

    ushort_t* p = (hs < NHEADS)
        ? qb  + (size_t)s * QD  + hs * HDIM
        : kvb + (size_t)s * KVL + (hs - NHEADS) * HDIM;
    float x0 = bf2f(p[i]);
    float x1 = bf2f(p[i + 64]);
    p[i]      = f2bf(x0 * c - x1 * sn);
    p[i + 64] = f2bf(x1 * c + x0 * sn);
}

// ---------------------------------------------------------------------------
// Flash attention v12 (R17 exact, proven 171us/424.6 total): split-K +
// single-barrier LDS double-buffer + gld16-direct K staging. R19's VTS=68
// pad is REVERTED: 136B rows put odd-row ds_read_b128 at 8 mod 16 ->
// misaligned (b128 needs 16B). vt stays [128][72] (16B-aligned rows).
// ---------------------------------------------------------------------------
__global__ __launch_bounds__(512, 4) void flash_mfma(
    const ushort_t* Q, const ushort_t* __restrict__ KV,
    const int* __restrict__ amask, ushort_t* O,
    ushort_t* __restrict__ Opart, float2* __restrict__ ML)
{
    __shared__ ushort_t ks[2][64 * 128];   // 32 KB: K dbuf, swizzled chunks
    __shared__ ushort_t vt[2][128 * 72];   // 36 KB: V^T dbuf, padded rows
    __shared__ float    bias[2][64];       // 0.5 KB

    const int t = threadIdx.x, w = t >> 6, lane = t & 63;
    const int quad = lane >> 4, l15 = lane & 15;
    const int h = blockIdx.x, kvh = h >> 2;
    const int s = blockIdx.y;                        // slot 0..71
    const int kcol = kvh * HDIM, vcol = KVD + kvh * HDIM;
    const float scale2 = 0.08838834764831845f * 1.44269504088896340f; // /sqrt(128)*log2e

    // slot -> (tile, chunk range, partial id)
    int tile, ktb, kte, pid;
    bool multi;
    if (s < 8)       { tile = 15 - s;        ktb = 0; kte = 2 * tile + 2; multi = false; pid = 0; }
    else if (s < 64) {
        int cs = s - 8;                               // 0..55
        int c;
        if (cs < 24) { tile = 16 + cs / 3; c = cs - (tile - 16) * 3; }
        else         { int d = cs - 24; tile = 24 + (d >> 2); c = d & 3; }
        int nkt = 2 * tile + 2;
        ktb = c * 16; kte = (ktb + 16 < nkt) ? ktb + 16 : nkt;
        multi = true; pid = h * NPART + cs;
    }
    else             { tile = 7 - (s - 64);  ktb = 0; kte = 2 * tile + 2; multi = false; pid = 0; }

    const int q0  = tile * 128;
    const int q0w = q0 + w * 16;

    // K gld16 map: 512 thr, 2 rounds; round r: row R = r*32 + (w*4+quad),
    // phys chunk l15, logical chunk = l15 ^ (R&7) (R&7 same both rounds).
    const int kRow = w * 4 + quad;                   // 0..31
    const int klc  = l15 ^ (kRow & 7);               // logical chunk
    // V staging map (reg transpose): keys 2vkp,2vkp+1, dims vdg*8..+8
    const int vkp  = t & 31,  vdg = t >> 5;

    // bpermute indices for P transpose: quad' = 2*(quad&1) + (t4>>1)
    int bpi[4];
#pragma unroll
    for (int t4 = 0; t4 < 4; t4++)
        bpi[t4] = ((2 * (quad & 1) + (t4 >> 1)) * 16 + l15) * 4;
    const bool hi_half = (quad >> 1) != 0;           // selects mt' = 2kc+1

    // physical chunk byte-offsets for QK^T frag reads: row&7 == l15&7
    int pco[4];
#pragma unroll
    for (int c = 0; c < 4; c++)
        pco[c] = ((4 * c + quad) ^ (l15 & 7)) * 8;

    // Q B-frags: qf[c] = Q[q0w + l15][c*32 + quad*8 ..+8]
    bf16x8 qf[4];
    {
        const ushort_t* qp = Q + (size_t)(q0w + l15) * QD + h * HDIM;
#pragma unroll
        for (int c = 0; c < 4; c++)
            qf[c] = *(const bf16x8*)(qp + c * 32 + quad * 8);
    }

    f32x4 accO[8];
#pragma unroll
    for (int j = 0; j < 8; j++) accO[j] = (f32x4)0.f;
    float m_s = -1e30f, l_s = 0.f;

    uint4 va, vb;
    float bst = 0.f;
    auto stage_k = [&](int kt, int b) {              // async K -> LDS (direct)
        const ushort_t* g0 = KV + (size_t)(kt * 64 + kRow) * KVL + kcol + klc * 8;
        gld16(g0, &ks[b][w * 512]);
        gld16(g0 + (size_t)32 * KVL, &ks[b][4096 + w * 512]);
    };
    auto vload = [&](int kt) {                       // V global -> regs
        const ushort_t* vp = KV + (size_t)(kt * 64 + 2 * vkp) * KVL + vcol + vdg * 8;
        va = *(const uint4_a*)vp;
        vb = *(const uint4_a*)(vp + KVL);
        bst = (t < 64) ? (amask[kt * 64 + t] ? 0.f : -1e30f) : 0.f;
    };
    auto vstore = [&](int b) {                       // regs -> vt[b] (transposed)
        unsigned aw[4] = {va.x, va.y, va.z, va.w};
        unsigned bw[4] = {vb.x, vb.y, vb.z, vb.w};
#pragma unroll
        for (int i = 0; i < 4; i++) {
            *(uint_a*)&vt[b][(vdg * 8 + 2 * i) * 72 + 2 * vkp] =
                (aw[i] & 0xFFFFu) | (bw[i] << 16);
            *(uint_a*)&vt[b][(vdg * 8 + 2 * i + 1) * 72 + 2 * vkp] =
                (aw[i] >> 16) | (bw[i] & 0xFFFF0000u);
        }
        if (t < 64) bias[b][t] = bst;
    };

    // prologue: stage tile ktb into buffer 0
    stage_k(ktb, 0);
    vload(ktb);
    vstore(0);
    __syncthreads();   // drains gld16 + ds_writes (compiler vmcnt/lgkmcnt)

    for (int kt = ktb; kt < kte; kt++) {
        const int cur = (kt - ktb) & 1;
        const int k0 = kt * 64;
        const bool more = (kt + 1 < kte);
        if (more) {                       // issue next-tile loads early (T14)
            stage_k(kt + 1, cur ^ 1);
            vload(kt + 1);
        }

        if (k0 <= q0w + 15) {             // tile not fully masked for this wave
            // ---- S^T = K Q^T ----
            f32x4 sx[4];
#pragma unroll
            for (int mt = 0; mt < 4; mt++) sx[mt] = (f32x4)0.f;
            __builtin_amdgcn_s_setprio(1);
#pragma unroll
            for (int c = 0; c < 4; c++)
#pragma unroll
                for (int mt = 0; mt < 4; mt++) {
                    bf16x8 kf = *(const bf16x8*)&ks[cur][(mt * 16 + l15) * 128 + pco[c]];
                    sx[mt] = __builtin_amdgcn_mfma_f32_16x16x32_bf16(kf, qf[c], sx[mt], 0, 0, 0);
                }
            __builtin_amdgcn_s_setprio(0);

            // ---- masked online softmax (exp2 domain); q-row = l15 ----
            const int qg = q0w + l15;
            const bool full = (k0 + 63 <= q0w);
            float p[4][4];
            float mx = -1e30f;
#pragma unroll
            for (int mt = 0; mt < 4; mt++) {
                float4 b4 = *(const float4_a*)&bias[cur][mt * 16 + quad * 4];
                float br[4] = {b4.x, b4.y, b4.z, b4.w};
#pragma unroll
                for (int r = 0; r < 4; r++) {
                    float v = fmaf(sx[mt][r], scale2, br[r]);
                    if (!full) {
                        int kg = k0 + mt * 16 + quad * 4 + r;
                        v = (kg > qg) ? -1e30f : v;
                    }
                    p[mt][r] = v;
                    mx = fmaxf(mx, v);
                }
            }
            mx = fmaxf(mx, __shfl_xor(mx, 16));
            mx = fmaxf(mx, __shfl_xor(mx, 32));
            // defer-max (T13): keep old max unless it grew by >8
            const bool renorm = !__all(mx <= m_s + 8.f);
            const float mnew = renorm ? fmaxf(m_s, mx) : m_s;
            float sum = 0.f;
            unsigned wlo[4], whi[4];
#pragma unroll
            for (int mt = 0; mt < 4; mt++) {
                float p0 = exp2f(p[mt][0] - mnew);
                float p1 = exp2f(p[mt][1] - mnew);
                float p2 = exp2f(p[mt][2] - mnew);
                float p3 = exp2f(p[mt][3] - mnew);
                sum += (p0 + p1) + (p2 + p3);
                wlo[mt] = cvt_pk(p0, p1);
                whi[mt] = cvt_pk(p2, p3);
            }
            sum += __shfl_xor(sum, 16);
            sum += __shfl_xor(sum, 32);

            if (renorm) {
                float alpha = exp2f(m_s - mnew);
                l_s *= alpha;
                float a0 = __shfl(alpha, quad * 4 + 0);
                float a1 = __shfl(alpha, quad * 4 + 1);
                float a2 = __shfl(alpha, quad * 4 + 2);
                float a3 = __shfl(alpha, quad * 4 + 3);
#pragma unroll
                for (int j = 0; j < 8; j++) {
                    f32x4 a = accO[j];
                    a[0] *= a0; a[1] *= a1; a[2] *= a2; a[3] *= a3;
                    accO[j] = a;
                }
            }
            m_s = mnew;
            l_s += sum;

            // ---- P transpose C->A layout via ds_bpermute; then O += P V ----
#pragma unroll
            for (int kc = 0; kc < 2; kc++) {
                union { unsigned u[4]; bf16x8 v; } pf;
#pragma unroll
                for (int t4 = 0; t4 < 4; t4++) {
                    unsigned slo = (t4 & 1) ? whi[2 * kc]     : wlo[2 * kc];
                    unsigned shi = (t4 & 1) ? whi[2 * kc + 1] : wlo[2 * kc + 1];
                    int ra = __builtin_amdgcn_ds_bpermute(bpi[t4], (int)slo);
                    int rb = __builtin_amdgcn_ds_bpermute(bpi[t4], (int)shi);
                    pf.u[t4] = (unsigned)(hi_half ? rb : ra);
                }
                __builtin_amdgcn_s_setprio(1);
#pragma unroll
                for (int n8 = 0; n8 < 8; n8++) {
                    bf16x8 vf = *(const bf16x8*)&vt[cur][(n8 * 16 + l15) * 72 + kc * 32 + quad * 8];
                    accO[n8] = __builtin_amdgcn_mfma_f32_16x16x32_bf16(pf.v, vf, accO[n8], 0, 0, 0);
                }
                __builtin_amdgcn_s_setprio(0);
            }
        }

        if (more) vstore(cur ^ 1);        // write-late: V regs -> other buffer
        __syncthreads();                  // single barrier: buf[cur] reads done,
                                          // gld16/ds_writes drained for next iter
    }

    if (!multi) {
        // ---- epilogue: normalize rows, store bf16 in-place over Q region ----
        float linv = 1.0f / l_s;
#pragma unroll
        for (int r = 0; r < 4; r++) {
            float lr = __shfl(linv, quad * 4 + r);
            int row = q0w + quad * 4 + r;
            ushort_t* op = O + (size_t)row * QD + h * HDIM;
#pragma unroll
            for (int n8 = 0; n8 < 8; n8++)
                op[n8 * 16 + l15] = f2bf(accO[n8][r] * lr);
        }
    } else {
        // ---- partial epilogue: unnormalized accO (bf16) + per-row (m,l) ----
        ushort_t* op = Opart + (size_t)pid * (128 * 128);
#pragma unroll
        for (int r = 0; r < 4; r++) {
            int row = w * 16 + quad * 4 + r;
#pragma unroll
            for (int n8 = 0; n8 < 8; n8++)
                op[row * 128 + n8 * 16 + l15] = f2bf(accO[n8][r]);
        }
        if (quad == 0)
            ML[pid * 128 + w * 16 + l15] = make_float2(m_s, l_s);
    }
}

// ---------------------------------------------------------------------------
// Merge split-K partials for tiles t=16..31 (coalesced): per-row weights
// wc[c][row] = 2^(m_c - M)/L precomputed in LDS; 8 lanes cover one row's
// 128B contiguous span (read AND write dense). 256 blocks (h, t), 256 thr.
// ---------------------------------------------------------------------------
__global__ __launch_bounds__(256) void combine_partials(
    const ushort_t* __restrict__ P, const float2* __restrict__ ML,
    ushort_t* __restrict__ O)
{
    __shared__ float wc[4][128];
    const int h = blockIdx.x >> 4, tt = blockIdx.x & 15, tile = 16 + tt;
    const int nc = (tile < 24) ? 3 : 4;
    const int pid0 = h * NPART + ((tile < 24) ? tt * 3 : 24 + (tile - 24) * 4);
    const int tid = threadIdx.x;

    if (tid < 128) {
        const int row = tid;
        float m_[4], l_[4];
        float M = -1e30f;
#pragma unroll
        for (int c = 0; c < 4; c++) {
            if (c < nc) {
                float2 v = *(const float2_a*)&ML[(pid0 + c) * 128 + row];
                m_[c] = v.x; l_[c] = v.y; M = fmaxf(M, v.x);
            } else { m_[c] = -1e30f; l_[c] = 0.f; }
        }
        float L = 0.f, wgt[4];
#pragma unroll
        for (int c = 0; c < 4; c++) { wgt[c] = exp2f(m_[c] - M); L += wgt[c] * l_[c]; }
        const float inv = 1.0f / L;
#pragma unroll
        for (int c = 0; c < 4; c++) wc[c][row] = (c < nc) ? wgt[c] * inv : 0.f;
    }
    __syncthreads();

#pragma unroll
    for (int p = 0; p < 4; p++) {
        const int idx = p * 256 + tid;
        const int row = idx >> 3, seg = idx & 7;     // 16 cols per seg
        const size_t pb = (size_t)row * 128 + seg * 16;
        float acc[16];
#pragma unroll
        for (int j = 0; j < 16; j++) acc[j] = 0.f;
#pragma unroll
        for (int c = 0; c < 4; c++) {
            if (c < nc) {
                const ushort_t* pp = P + (size_t)(pid0 + c) * (128 * 128) + pb;
                uint4 v0 = *(const uint4_a*)pp;
                uint4 v1 = *(const uint4_a*)(pp + 8);
                const float wv_ = wc[c][row];
                unsigned u[8] = {v0.x, v0.y, v0.z, v0.w, v1.x, v1.y, v1.z, v1.w};
#pragma unroll
                for (int j = 0; j < 8; j++) {
                    acc[2 * j]     += wv_ * bf2f((ushort_t)(u[j] & 0xFFFFu));
                    acc[2 * j + 1] += wv_ * bf2f((ushort_t)(u[j] >> 16));
                }
            }
        }
        ushort_t* op = O + (size_t)(tile * 128 + row) * QD + h * HDIM + seg * 16;
        uint4 o0, o1;
        o0.x = pack2(acc[0],  acc[1]);  o0.y = pack2(acc[2],  acc[3]);
        o0.z = pack2(acc[4],  acc[5]);  o0.w = pack2(acc[6],  acc[7]);
        o1.x = pack2(acc[8],  acc[9]);  o1.y = pack2(acc[10], acc[11]);
        o1.z = pack2(acc[12], acc[13]); o1.w = pack2(acc[14], acc[15]);
        *(uint4_a*)op       = o0;
        *(uint4_a*)(op + 8) = o1;
    }
}

// ---------------------------------------------------------------------------
// Memory plan: ws = qbuf/att 16MB | kvbuf (k|v interleaved) 8MB | (woT 8MB
// overwrites kvbuf after flash+combine). d_out scratch: wqkvT 12MB | xb 16MB
// until QKV GEMM; then flash partials: Opart 28MB | ML 0.9MB; O-GEMM output
// overwrites after combine.
// ---------------------------------------------------------------------------
extern "C" void kernel_launch(void* const* d_in, const int* in_sizes, int n_in,
                              void* d_out, int out_size, void* d_ws, size_t ws_size,
                              hipStream_t stream)
{
    const float* x     = (const float*)d_in[0];
    const int*   amask = (const int*)d_in[1];
    const int*   pos   = (const int*)d_in[2];
    const float* wq    = (const float*)d_in[3];
    const float* wk    = (const float*)d_in[4];
    const float* wv    = (const float*)d_in[5];
    const float* wo    = (const float*)d_in[6];
    float* out = (float*)d_out;

    ushort_t* wqkvT = (ushort_t*)d_out;                    // [3072][2048] bf16
    ushort_t* xb    = wqkvT + (size_t)3072 * HID;          // [4096][2048] bf16

    ushort_t* qbuf  = (ushort_t*)d_ws;                     // [4096][2048]
    ushort_t* kvbuf = qbuf + (size_t)SEQ * QD;             // [4096][1024] k|v
    ushort_t* woT   = kvbuf;                               // [2048][2048] after flash

    // split-K partials live in d_out during attention
    ushort_t* opart = (ushort_t*)d_out;                    // 896 x 128 x 128 bf16 = 28MB
    float2*   mlbuf = (float2*)((char*)d_out + (size_t)16 * NPART * 128 * 128 * 2);

    // fused: X cast (blocks 0..4095) + wq|wk|wv transpose (blocks 4096..10239)
    prep<<<10240, 256, 0, stream>>>(x, xb, wq, wk, wv, wqkvT);

    // fused QKV projection: cols [0,2048) -> qbuf, [2048,3072) -> kvbuf
    gemm_mfma<<<dim3(3072 / 128, SEQ / 128), 256, 0, stream>>>(
        xb, HID, wqkvT, HID, qbuf, QD, kvbuf, KVL, QD, 3072, HID, 0);

    // fused RoPE on Q and KV in one launch
    rope_both<<<SEQ * (NHEADS + NKVH) * 64 / 256, 256, 0, stream>>>(qbuf, kvbuf, pos);

    // split-K flash: 16 heads x 72 slots = 1152 blocks, 2 resident/CU + backfill
    flash_mfma<<<dim3(NHEADS, 72), 512, 0, stream>>>(
        qbuf, kvbuf, amask, qbuf, opart, mlbuf);
    combine_partials<<<dim3(256), 256, 0, stream>>>(opart, mlbuf, qbuf);

    transpose_cast<<<dim3(QD / 32, HID / 32), 256, 0, stream>>>(wo, woT, QD, HID);
    gemm_mfma<<<dim3(HID / 128, SEQ / 128), 256, 0, stream>>>(
        qbuf, QD, woT, QD, out, HID, out, HID, HID, HID, QD, 1);
}